// Round 1
// baseline (882.052 us; speedup 1.0000x reference)
//
#include <hip/hip_runtime.h>
#include <cstddef>

#define NND 100000
#define NED 1600000
#define NEP (NED + NND)

// ---------------- edge dtype detection ----------------
// If storage is int64: every value in [0, NND). If int32: int64-reads combine
// two indices -> huge values -> flag=0.
__global__ void k_detect(const long long* __restrict__ ei, int* __restrict__ flag) {
    __shared__ int ok;
    if (threadIdx.x == 0) ok = 1;
    __syncthreads();
    for (int i = threadIdx.x; i < 2048; i += blockDim.x) {
        long long v = ei[i];
        if (v < 0 || v >= NND) ok = 0;
    }
    __syncthreads();
    if (threadIdx.x == 0) *flag = ok;
}

__device__ __forceinline__ void load_edge(const void* ei, int is64, int e, int& src, int& dst) {
    if (e >= NED) { src = dst = e - NED; return; }  // self-loop
    if (is64) {
        const long long* p = (const long long*)ei;
        src = (int)p[e];
        dst = (int)p[NED + e];
    } else {
        const int* p = (const int*)ei;
        src = p[e];
        dst = p[NED + e];
    }
}

// ---------------- degree / norm ----------------
__global__ void k_deg(const void* __restrict__ ei, const int* __restrict__ flag,
                      int* __restrict__ deg) {
    int e = blockIdx.x * 256 + threadIdx.x;
    if (e >= NEP) return;
    int s, d;
    load_edge(ei, *flag, e, s, d);
    atomicAdd(&deg[d], 1);
}

__global__ void k_dinv(const int* __restrict__ deg, float* __restrict__ dinv) {
    int n = blockIdx.x * 256 + threadIdx.x;
    if (n >= NND) return;
    int d = deg[n];
    if (d < 1) d = 1;
    dinv[n] = 1.0f / sqrtf((float)d);
}

// ---------------- exclusive scan of deg -> row_off ----------------
__global__ __launch_bounds__(1024) void k_scan1(const int* __restrict__ deg,
                                                int* __restrict__ row_off,
                                                int* __restrict__ bsum) {
    __shared__ int sh[1024];
    int i = blockIdx.x * 1024 + threadIdx.x;
    int v = (i < NND) ? deg[i] : 0;
    sh[threadIdx.x] = v;
    __syncthreads();
    for (int off = 1; off < 1024; off <<= 1) {
        int t = 0;
        if ((int)threadIdx.x >= off) t = sh[threadIdx.x - off];
        __syncthreads();
        sh[threadIdx.x] += t;
        __syncthreads();
    }
    if (i < NND) row_off[i] = sh[threadIdx.x] - v;  // exclusive
    if (threadIdx.x == 1023) bsum[blockIdx.x] = sh[1023];
}

__global__ void k_scan2(int* __restrict__ bsum, int nb) {
    __shared__ int sh[128];
    int t = threadIdx.x;
    int orig = (t < nb) ? bsum[t] : 0;
    sh[t] = orig;
    __syncthreads();
    for (int off = 1; off < 128; off <<= 1) {
        int v = 0;
        if (t >= off) v = sh[t - off];
        __syncthreads();
        sh[t] += v;
        __syncthreads();
    }
    if (t < nb) bsum[t] = sh[t] - orig;  // exclusive block offsets
}

__global__ void k_scan3(int* __restrict__ row_off, const int* __restrict__ bsum) {
    int i = blockIdx.x * 256 + threadIdx.x;
    if (i < NND) row_off[i] += bsum[i >> 10];
    if (i == 0) row_off[NND] = NEP;
}

// ---------------- CSR fill (col = src, sorted by dst) ----------------
__global__ void k_fill(const void* __restrict__ ei, const int* __restrict__ flag,
                       const int* __restrict__ row_off, int* __restrict__ cursor,
                       int* __restrict__ col) {
    int e = blockIdx.x * 256 + threadIdx.x;
    if (e >= NEP) return;
    int s, d;
    load_edge(ei, *flag, e, s, d);
    int pos = row_off[d] + atomicAdd(&cursor[d], 1);
    col[pos] = s;
}

// ---------------- aggregation: out[n] = dinv[n] * sum_e dinv[src] * in[src] (+bias, relu) ----
template <int C, bool BIAS, bool RELU>
__global__ void k_agg(const float* __restrict__ in, float* __restrict__ out,
                      const int* __restrict__ row_off, const int* __restrict__ col,
                      const float* __restrict__ dinv, const float* __restrict__ bias) {
    int n = blockIdx.x;
    int c = threadIdx.x;
    int s = row_off[n], e = row_off[n + 1];
    float acc = 0.f;
    for (int k = s; k < e; ++k) {
        int src = col[k];
        acc = fmaf(dinv[src], in[(size_t)src * C + c], acc);
    }
    float v = acc * dinv[n];
    if (BIAS) v += bias[c];
    if (RELU) v = fmaxf(v, 0.f);
    out[(size_t)n * C + c] = v;
}

// ---------------- f32 register-tiled GEMM: out[nrows,COUT] = in[nrows,K] @ W[K,COUT] ----
template <int K, int COUT, bool BIAS>
__global__ __launch_bounds__(256) void k_gemm(const float* __restrict__ in,
                                              const float* __restrict__ W,
                                              const float* __restrict__ bias,
                                              float* __restrict__ out, int nrows) {
    constexpr int TC = COUT / 4;   // thread-cols
    constexpr int TR = 256 / TC;   // thread-rows
    constexpr int ROWS = TR * 4;   // rows per block
    constexpr int KC = 32;         // k-chunk
    constexpr int KQ = KC / 4;

    __shared__ float Ws[KC][COUT];
    __shared__ float xsT[KC][ROWS];

    const int t = threadIdx.x;
    const int tc = t % TC;
    const int tr = t / TC;
    const int row0 = blockIdx.x * ROWS;

    float acc[4][4];
#pragma unroll
    for (int i = 0; i < 4; ++i)
#pragma unroll
        for (int j = 0; j < 4; ++j) acc[i][j] = 0.f;

    for (int kc = 0; kc < K; kc += KC) {
        __syncthreads();
        {
            constexpr int TOT = KC * COUT / 4;
            const float4* Wv = (const float4*)(W + (size_t)kc * COUT);
            float4* Wsv = (float4*)(&Ws[0][0]);
            for (int i = t; i < TOT; i += 256) Wsv[i] = Wv[i];
        }
        {
            for (int idx = t; idx < ROWS * KQ; idx += 256) {
                int r = idx / KQ, kq = idx % KQ;
                int row = row0 + r;
                if (row >= nrows) row = nrows - 1;
                float4 v = *(const float4*)(in + (size_t)row * K + kc + kq * 4);
                int kk = kq * 4;
                xsT[kk + 0][r] = v.x;
                xsT[kk + 1][r] = v.y;
                xsT[kk + 2][r] = v.z;
                xsT[kk + 3][r] = v.w;
            }
        }
        __syncthreads();
#pragma unroll
        for (int k = 0; k < KC; ++k) {
            float4 xv = *(const float4*)(&xsT[k][tr * 4]);
            float4 wv = *(const float4*)(&Ws[k][tc * 4]);
            acc[0][0] = fmaf(xv.x, wv.x, acc[0][0]);
            acc[0][1] = fmaf(xv.x, wv.y, acc[0][1]);
            acc[0][2] = fmaf(xv.x, wv.z, acc[0][2]);
            acc[0][3] = fmaf(xv.x, wv.w, acc[0][3]);
            acc[1][0] = fmaf(xv.y, wv.x, acc[1][0]);
            acc[1][1] = fmaf(xv.y, wv.y, acc[1][1]);
            acc[1][2] = fmaf(xv.y, wv.z, acc[1][2]);
            acc[1][3] = fmaf(xv.y, wv.w, acc[1][3]);
            acc[2][0] = fmaf(xv.z, wv.x, acc[2][0]);
            acc[2][1] = fmaf(xv.z, wv.y, acc[2][1]);
            acc[2][2] = fmaf(xv.z, wv.z, acc[2][2]);
            acc[2][3] = fmaf(xv.z, wv.w, acc[2][3]);
            acc[3][0] = fmaf(xv.w, wv.x, acc[3][0]);
            acc[3][1] = fmaf(xv.w, wv.y, acc[3][1]);
            acc[3][2] = fmaf(xv.w, wv.z, acc[3][2]);
            acc[3][3] = fmaf(xv.w, wv.w, acc[3][3]);
        }
    }

    float4 bv = make_float4(0.f, 0.f, 0.f, 0.f);
    if constexpr (BIAS) bv = *(const float4*)(bias + tc * 4);
#pragma unroll
    for (int i = 0; i < 4; ++i) {
        int row = row0 + tr * 4 + i;
        if (row < nrows) {
            float4 o;
            o.x = acc[i][0] + bv.x;
            o.y = acc[i][1] + bv.y;
            o.z = acc[i][2] + bv.z;
            o.w = acc[i][3] + bv.w;
            *(float4*)(out + (size_t)row * COUT + tc * 4) = o;
        }
    }
}

// ---------------- host ----------------
extern "C" void kernel_launch(void* const* d_in, const int* in_sizes, int n_in,
                              void* d_out, int out_size, void* d_ws, size_t ws_size,
                              hipStream_t stream) {
    const float* x = (const float*)d_in[0];
    const void* ei = d_in[1];
    const float* W1 = (const float*)d_in[2];
    const float* b1 = (const float*)d_in[3];
    const float* W2 = (const float*)d_in[4];
    const float* b2 = (const float*)d_in[5];
    const float* W3 = (const float*)d_in[6];
    const float* b3 = (const float*)d_in[7];
    float* out = (float*)d_out;

    char* ws = (char*)d_ws;
    size_t off = 0;
    auto alloc = [&](size_t bytes) -> void* {
        void* p = ws + off;
        off = (off + bytes + 255) & ~(size_t)255;
        return p;
    };

    int* flag = (int*)alloc(sizeof(int));
    int* deg = (int*)alloc((size_t)NND * 4);
    int* cursor = (int*)alloc((size_t)NND * 4);
    int* row_off = (int*)alloc((size_t)(NND + 1) * 4);
    int* bsum = (int*)alloc(512);
    float* dinv = (float*)alloc((size_t)NND * 4);
    int* col = (int*)alloc((size_t)NEP * 4);
    float* AX = (float*)alloc((size_t)NND * 128 * 4);  // aliased as H2 later
    float* A1 = (float*)alloc((size_t)NND * 256 * 4);  // aliased as H3 later
    float* A2 = (float*)alloc((size_t)NND * 128 * 4);
    float* H2 = AX;  // AX dead after gemm1
    float* H3 = A1;  // A1 dead after gemm2

    hipMemsetAsync(deg, 0, (size_t)NND * 4, stream);
    hipMemsetAsync(cursor, 0, (size_t)NND * 4, stream);

    k_detect<<<1, 256, 0, stream>>>((const long long*)ei, flag);

    const int gE = (NEP + 255) / 256;
    const int gN = (NND + 255) / 256;
    k_deg<<<gE, 256, 0, stream>>>(ei, flag, deg);
    k_dinv<<<gN, 256, 0, stream>>>(deg, dinv);

    const int NB = (NND + 1023) / 1024;  // 98
    k_scan1<<<NB, 1024, 0, stream>>>(deg, row_off, bsum);
    k_scan2<<<1, 128, 0, stream>>>(bsum, NB);
    k_scan3<<<gN, 256, 0, stream>>>(row_off, bsum);

    k_fill<<<gE, 256, 0, stream>>>(ei, flag, row_off, cursor, col);

    // L1: AX = Ahat @ X ; A1 = AX @ W1 + b1
    k_agg<128, false, false><<<NND, 128, 0, stream>>>(x, AX, row_off, col, dinv, nullptr);
    k_gemm<128, 256, true><<<(NND + 15) / 16, 256, 0, stream>>>(AX, W1, b1, A1, NND);

    // L2: H2 = A1 @ W2 ; A2 = relu(Ahat @ H2 + b2)
    k_gemm<256, 128, false><<<(NND + 31) / 32, 256, 0, stream>>>(A1, W2, nullptr, H2, NND);
    k_agg<128, true, true><<<NND, 128, 0, stream>>>(H2, A2, row_off, col, dinv, b2);

    // L3: H3 = A2 @ W3 ; out = Ahat @ H3 + b3
    k_gemm<128, 64, false><<<(NND + 63) / 64, 256, 0, stream>>>(A2, W3, nullptr, H3, NND);
    k_agg<64, true, false><<<NND, 64, 0, stream>>>(H3, out, row_off, col, dinv, b3);
}

// Round 2
// 728.142 us; speedup vs baseline: 1.2114x; 1.2114x over previous
//
#include <hip/hip_runtime.h>
#include <cstddef>

#define NND 100000
#define NED 1600000
#define NEP (NED + NND)

// ---------------- edge dtype detection ----------------
__global__ void k_detect(const long long* __restrict__ ei, int* __restrict__ flag) {
    __shared__ int ok;
    if (threadIdx.x == 0) ok = 1;
    __syncthreads();
    for (int i = threadIdx.x; i < 2048; i += blockDim.x) {
        long long v = ei[i];
        if (v < 0 || v >= NND) ok = 0;
    }
    __syncthreads();
    if (threadIdx.x == 0) *flag = ok;
}

__device__ __forceinline__ void load_edge(const void* ei, int is64, int e, int& src, int& dst) {
    if (e >= NED) { src = dst = e - NED; return; }  // self-loop
    if (is64) {
        const long long* p = (const long long*)ei;
        src = (int)p[e];
        dst = (int)p[NED + e];
    } else {
        const int* p = (const int*)ei;
        src = p[e];
        dst = p[NED + e];
    }
}

// ---------------- degree / norm ----------------
__global__ void k_deg(const void* __restrict__ ei, const int* __restrict__ flag,
                      int* __restrict__ deg) {
    int e = blockIdx.x * 256 + threadIdx.x;
    if (e >= NEP) return;
    int s, d;
    load_edge(ei, *flag, e, s, d);
    atomicAdd(&deg[d], 1);
}

__global__ void k_dinv(const int* __restrict__ deg, float* __restrict__ dinv) {
    int n = blockIdx.x * 256 + threadIdx.x;
    if (n >= NND) return;
    int d = deg[n];
    if (d < 1) d = 1;
    dinv[n] = 1.0f / sqrtf((float)d);
}

// ---------------- exclusive scan of deg -> row_off ----------------
__global__ __launch_bounds__(1024) void k_scan1(const int* __restrict__ deg,
                                                int* __restrict__ row_off,
                                                int* __restrict__ bsum) {
    __shared__ int sh[1024];
    int i = blockIdx.x * 1024 + threadIdx.x;
    int v = (i < NND) ? deg[i] : 0;
    sh[threadIdx.x] = v;
    __syncthreads();
    for (int off = 1; off < 1024; off <<= 1) {
        int t = 0;
        if ((int)threadIdx.x >= off) t = sh[threadIdx.x - off];
        __syncthreads();
        sh[threadIdx.x] += t;
        __syncthreads();
    }
    if (i < NND) row_off[i] = sh[threadIdx.x] - v;  // exclusive
    if (threadIdx.x == 1023) bsum[blockIdx.x] = sh[1023];
}

__global__ void k_scan2(int* __restrict__ bsum, int nb) {
    __shared__ int sh[128];
    int t = threadIdx.x;
    int orig = (t < nb) ? bsum[t] : 0;
    sh[t] = orig;
    __syncthreads();
    for (int off = 1; off < 128; off <<= 1) {
        int v = 0;
        if (t >= off) v = sh[t - off];
        __syncthreads();
        sh[t] += v;
        __syncthreads();
    }
    if (t < nb) bsum[t] = sh[t] - orig;  // exclusive block offsets
}

__global__ void k_scan3(int* __restrict__ row_off, const int* __restrict__ bsum) {
    int i = blockIdx.x * 256 + threadIdx.x;
    if (i < NND) row_off[i] += bsum[i >> 10];
    if (i == 0) row_off[NND] = NEP;
}

// ---------------- CSR fill (col = src, sorted by dst) ----------------
__global__ void k_fill(const void* __restrict__ ei, const int* __restrict__ flag,
                       const int* __restrict__ row_off, int* __restrict__ cursor,
                       int* __restrict__ col) {
    int e = blockIdx.x * 256 + threadIdx.x;
    if (e >= NEP) return;
    int s, d;
    load_edge(ei, *flag, e, s, d);
    int pos = row_off[d] + atomicAdd(&cursor[d], 1);
    col[pos] = s;
}

// ---------------- aggregation ----------------
// out[n] = dinv[n] * sum_{src in N(n)} dinv[src] * in[src]  (+bias, relu)
// Block = C threads (one node). NG=4 edge-groups of C/4 lanes; each group
// gathers float4 rows (one coalesced 512B/256B request per edge); 2-way
// unroll -> 8 independent gather chains per block for latency hiding.
template <int C, bool BIAS, bool RELU>
__global__ __launch_bounds__(C) void k_agg(const float* __restrict__ in, float* __restrict__ out,
                      const int* __restrict__ row_off, const int* __restrict__ col,
                      const float* __restrict__ dinv, const float* __restrict__ bias) {
    constexpr int LPG = C / 4;  // lanes per group
    constexpr int NG = 4;       // edge groups
    __shared__ float4 sh[NG][LPG];

    const int n = blockIdx.x;
    const int t = threadIdx.x;
    const int g = t / LPG;
    const int l = t % LPG;
    const int s = row_off[n], e = row_off[n + 1];
    const float4* __restrict__ in4 = (const float4*)in;

    float4 a0 = make_float4(0.f, 0.f, 0.f, 0.f);
    float4 a1 = make_float4(0.f, 0.f, 0.f, 0.f);

    int k = s + g;
    for (; k + NG < e; k += 2 * NG) {
        int s0 = col[k];
        int s1 = col[k + NG];
        float d0 = dinv[s0];
        float d1 = dinv[s1];
        float4 v0 = in4[(size_t)s0 * LPG + l];
        float4 v1 = in4[(size_t)s1 * LPG + l];
        a0.x = fmaf(d0, v0.x, a0.x);
        a0.y = fmaf(d0, v0.y, a0.y);
        a0.z = fmaf(d0, v0.z, a0.z);
        a0.w = fmaf(d0, v0.w, a0.w);
        a1.x = fmaf(d1, v1.x, a1.x);
        a1.y = fmaf(d1, v1.y, a1.y);
        a1.z = fmaf(d1, v1.z, a1.z);
        a1.w = fmaf(d1, v1.w, a1.w);
    }
    if (k < e) {
        int s0 = col[k];
        float d0 = dinv[s0];
        float4 v0 = in4[(size_t)s0 * LPG + l];
        a0.x = fmaf(d0, v0.x, a0.x);
        a0.y = fmaf(d0, v0.y, a0.y);
        a0.z = fmaf(d0, v0.z, a0.z);
        a0.w = fmaf(d0, v0.w, a0.w);
    }
    a0.x += a1.x; a0.y += a1.y; a0.z += a1.z; a0.w += a1.w;
    sh[g][l] = a0;
    __syncthreads();
    if (g == 0) {
        float4 r = sh[0][l];
        float4 r1 = sh[1][l];
        float4 r2 = sh[2][l];
        float4 r3 = sh[3][l];
        r.x += r1.x + r2.x + r3.x;
        r.y += r1.y + r2.y + r3.y;
        r.z += r1.z + r2.z + r3.z;
        r.w += r1.w + r2.w + r3.w;
        float dn = dinv[n];
        r.x *= dn; r.y *= dn; r.z *= dn; r.w *= dn;
        if constexpr (BIAS) {
            float4 bv = ((const float4*)bias)[l];
            r.x += bv.x; r.y += bv.y; r.z += bv.z; r.w += bv.w;
        }
        if constexpr (RELU) {
            r.x = fmaxf(r.x, 0.f); r.y = fmaxf(r.y, 0.f);
            r.z = fmaxf(r.z, 0.f); r.w = fmaxf(r.w, 0.f);
        }
        ((float4*)out)[(size_t)n * LPG + l] = r;
    }
}

// ---------------- f32 register-tiled GEMM: out[nrows,COUT] = in[nrows,K] @ W[K,COUT] ----
template <int K, int COUT, bool BIAS>
__global__ __launch_bounds__(256) void k_gemm(const float* __restrict__ in,
                                              const float* __restrict__ W,
                                              const float* __restrict__ bias,
                                              float* __restrict__ out, int nrows) {
    constexpr int TC = COUT / 4;   // thread-cols
    constexpr int TR = 256 / TC;   // thread-rows
    constexpr int ROWS = TR * 4;   // rows per block
    constexpr int KC = 32;         // k-chunk
    constexpr int KQ = KC / 4;

    __shared__ float Ws[KC][COUT];
    __shared__ float xsT[KC][ROWS];

    const int t = threadIdx.x;
    const int tc = t % TC;
    const int tr = t / TC;
    const int row0 = blockIdx.x * ROWS;

    float acc[4][4];
#pragma unroll
    for (int i = 0; i < 4; ++i)
#pragma unroll
        for (int j = 0; j < 4; ++j) acc[i][j] = 0.f;

    for (int kc = 0; kc < K; kc += KC) {
        __syncthreads();
        {
            constexpr int TOT = KC * COUT / 4;
            const float4* Wv = (const float4*)(W + (size_t)kc * COUT);
            float4* Wsv = (float4*)(&Ws[0][0]);
            for (int i = t; i < TOT; i += 256) Wsv[i] = Wv[i];
        }
        {
            for (int idx = t; idx < ROWS * KQ; idx += 256) {
                int r = idx / KQ, kq = idx % KQ;
                int row = row0 + r;
                if (row >= nrows) row = nrows - 1;
                float4 v = *(const float4*)(in + (size_t)row * K + kc + kq * 4);
                int kk = kq * 4;
                xsT[kk + 0][r] = v.x;
                xsT[kk + 1][r] = v.y;
                xsT[kk + 2][r] = v.z;
                xsT[kk + 3][r] = v.w;
            }
        }
        __syncthreads();
#pragma unroll
        for (int k = 0; k < KC; ++k) {
            float4 xv = *(const float4*)(&xsT[k][tr * 4]);
            float4 wv = *(const float4*)(&Ws[k][tc * 4]);
            acc[0][0] = fmaf(xv.x, wv.x, acc[0][0]);
            acc[0][1] = fmaf(xv.x, wv.y, acc[0][1]);
            acc[0][2] = fmaf(xv.x, wv.z, acc[0][2]);
            acc[0][3] = fmaf(xv.x, wv.w, acc[0][3]);
            acc[1][0] = fmaf(xv.y, wv.x, acc[1][0]);
            acc[1][1] = fmaf(xv.y, wv.y, acc[1][1]);
            acc[1][2] = fmaf(xv.y, wv.z, acc[1][2]);
            acc[1][3] = fmaf(xv.y, wv.w, acc[1][3]);
            acc[2][0] = fmaf(xv.z, wv.x, acc[2][0]);
            acc[2][1] = fmaf(xv.z, wv.y, acc[2][1]);
            acc[2][2] = fmaf(xv.z, wv.z, acc[2][2]);
            acc[2][3] = fmaf(xv.z, wv.w, acc[2][3]);
            acc[3][0] = fmaf(xv.w, wv.x, acc[3][0]);
            acc[3][1] = fmaf(xv.w, wv.y, acc[3][1]);
            acc[3][2] = fmaf(xv.w, wv.z, acc[3][2]);
            acc[3][3] = fmaf(xv.w, wv.w, acc[3][3]);
        }
    }

    float4 bv = make_float4(0.f, 0.f, 0.f, 0.f);
    if constexpr (BIAS) bv = *(const float4*)(bias + tc * 4);
#pragma unroll
    for (int i = 0; i < 4; ++i) {
        int row = row0 + tr * 4 + i;
        if (row < nrows) {
            float4 o;
            o.x = acc[i][0] + bv.x;
            o.y = acc[i][1] + bv.y;
            o.z = acc[i][2] + bv.z;
            o.w = acc[i][3] + bv.w;
            *(float4*)(out + (size_t)row * COUT + tc * 4) = o;
        }
    }
}

// ---------------- host ----------------
extern "C" void kernel_launch(void* const* d_in, const int* in_sizes, int n_in,
                              void* d_out, int out_size, void* d_ws, size_t ws_size,
                              hipStream_t stream) {
    const float* x = (const float*)d_in[0];
    const void* ei = d_in[1];
    const float* W1 = (const float*)d_in[2];
    const float* b1 = (const float*)d_in[3];
    const float* W2 = (const float*)d_in[4];
    const float* b2 = (const float*)d_in[5];
    const float* W3 = (const float*)d_in[6];
    const float* b3 = (const float*)d_in[7];
    float* out = (float*)d_out;

    char* ws = (char*)d_ws;
    size_t off = 0;
    auto alloc = [&](size_t bytes) -> void* {
        void* p = ws + off;
        off = (off + bytes + 255) & ~(size_t)255;
        return p;
    };

    int* flag = (int*)alloc(sizeof(int));
    int* deg = (int*)alloc((size_t)NND * 4);
    int* cursor = (int*)alloc((size_t)NND * 4);
    int* row_off = (int*)alloc((size_t)(NND + 1) * 4);
    int* bsum = (int*)alloc(512);
    float* dinv = (float*)alloc((size_t)NND * 4);
    int* col = (int*)alloc((size_t)NEP * 4);
    float* AX = (float*)alloc((size_t)NND * 128 * 4);  // aliased as H2 later
    float* A1 = (float*)alloc((size_t)NND * 256 * 4);  // aliased as H3 later
    float* A2 = (float*)alloc((size_t)NND * 128 * 4);
    float* H2 = AX;  // AX dead after gemm1
    float* H3 = A1;  // A1 dead after gemm2

    hipMemsetAsync(deg, 0, (size_t)NND * 4, stream);
    hipMemsetAsync(cursor, 0, (size_t)NND * 4, stream);

    k_detect<<<1, 256, 0, stream>>>((const long long*)ei, flag);

    const int gE = (NEP + 255) / 256;
    const int gN = (NND + 255) / 256;
    k_deg<<<gE, 256, 0, stream>>>(ei, flag, deg);
    k_dinv<<<gN, 256, 0, stream>>>(deg, dinv);

    const int NB = (NND + 1023) / 1024;  // 98
    k_scan1<<<NB, 1024, 0, stream>>>(deg, row_off, bsum);
    k_scan2<<<1, 128, 0, stream>>>(bsum, NB);
    k_scan3<<<gN, 256, 0, stream>>>(row_off, bsum);

    k_fill<<<gE, 256, 0, stream>>>(ei, flag, row_off, cursor, col);

    // L1: AX = Ahat @ X ; A1 = AX @ W1 + b1
    k_agg<128, false, false><<<NND, 128, 0, stream>>>(x, AX, row_off, col, dinv, nullptr);
    k_gemm<128, 256, true><<<(NND + 15) / 16, 256, 0, stream>>>(AX, W1, b1, A1, NND);

    // L2: H2 = A1 @ W2 ; A2 = relu(Ahat @ H2 + b2)
    k_gemm<256, 128, false><<<(NND + 31) / 32, 256, 0, stream>>>(A1, W2, nullptr, H2, NND);
    k_agg<128, true, true><<<NND, 128, 0, stream>>>(H2, A2, row_off, col, dinv, b2);

    // L3: H3 = A2 @ W3 ; out = Ahat @ H3 + b3
    k_gemm<128, 64, false><<<(NND + 63) / 64, 256, 0, stream>>>(A2, W3, nullptr, H3, NND);
    k_agg<64, true, false><<<NND, 64, 0, stream>>>(H3, out, row_off, col, dinv, b3);
}

// Round 3
// 713.173 us; speedup vs baseline: 1.2368x; 1.0210x over previous
//
#include <hip/hip_runtime.h>
#include <cstddef>

#define NND 100000
#define NED 1600000
#define NEP (NED + NND)

// ---------------- edge dtype detection ----------------
__global__ void k_detect(const long long* __restrict__ ei, int* __restrict__ flag) {
    __shared__ int ok;
    if (threadIdx.x == 0) ok = 1;
    __syncthreads();
    for (int i = threadIdx.x; i < 2048; i += blockDim.x) {
        long long v = ei[i];
        if (v < 0 || v >= NND) ok = 0;
    }
    __syncthreads();
    if (threadIdx.x == 0) *flag = ok;
}

__device__ __forceinline__ void load_edge(const void* ei, int is64, int e, int& src, int& dst) {
    if (e >= NED) { src = dst = e - NED; return; }  // self-loop
    if (is64) {
        const long long* p = (const long long*)ei;
        src = (int)p[e];
        dst = (int)p[NED + e];
    } else {
        const int* p = (const int*)ei;
        src = p[e];
        dst = p[NED + e];
    }
}

// ---------------- degree / norm ----------------
__global__ void k_deg(const void* __restrict__ ei, const int* __restrict__ flag,
                      int* __restrict__ deg) {
    int e = blockIdx.x * 256 + threadIdx.x;
    if (e >= NEP) return;
    int s, d;
    load_edge(ei, *flag, e, s, d);
    atomicAdd(&deg[d], 1);
}

__global__ void k_dinv(const int* __restrict__ deg, float* __restrict__ dinv) {
    int n = blockIdx.x * 256 + threadIdx.x;
    if (n >= NND) return;
    int d = deg[n];
    if (d < 1) d = 1;
    dinv[n] = 1.0f / sqrtf((float)d);
}

// ---------------- exclusive scan of deg -> row_off ----------------
__global__ __launch_bounds__(1024) void k_scan1(const int* __restrict__ deg,
                                                int* __restrict__ row_off,
                                                int* __restrict__ bsum) {
    __shared__ int sh[1024];
    int i = blockIdx.x * 1024 + threadIdx.x;
    int v = (i < NND) ? deg[i] : 0;
    sh[threadIdx.x] = v;
    __syncthreads();
    for (int off = 1; off < 1024; off <<= 1) {
        int t = 0;
        if ((int)threadIdx.x >= off) t = sh[threadIdx.x - off];
        __syncthreads();
        sh[threadIdx.x] += t;
        __syncthreads();
    }
    if (i < NND) row_off[i] = sh[threadIdx.x] - v;  // exclusive
    if (threadIdx.x == 1023) bsum[blockIdx.x] = sh[1023];
}

__global__ void k_scan2(int* __restrict__ bsum, int nb) {
    __shared__ int sh[128];
    int t = threadIdx.x;
    int orig = (t < nb) ? bsum[t] : 0;
    sh[t] = orig;
    __syncthreads();
    for (int off = 1; off < 128; off <<= 1) {
        int v = 0;
        if (t >= off) v = sh[t - off];
        __syncthreads();
        sh[t] += v;
        __syncthreads();
    }
    if (t < nb) bsum[t] = sh[t] - orig;  // exclusive block offsets
}

__global__ void k_scan3(int* __restrict__ row_off, const int* __restrict__ bsum) {
    int i = blockIdx.x * 256 + threadIdx.x;
    if (i < NND) row_off[i] += bsum[i >> 10];
    if (i == 0) row_off[NND] = NEP;
}

// ---------------- CSR fill (col = src, sorted by dst) ----------------
__global__ void k_fill(const void* __restrict__ ei, const int* __restrict__ flag,
                       const int* __restrict__ row_off, int* __restrict__ cursor,
                       int* __restrict__ col) {
    int e = blockIdx.x * 256 + threadIdx.x;
    if (e >= NEP) return;
    int s, d;
    load_edge(ei, *flag, e, s, d);
    int pos = row_off[d] + atomicAdd(&cursor[d], 1);
    col[pos] = s;
}

// ---------------- aggregation ----------------
// out[n] = dinv[n] * sum_{src in N(n)} dinv[src] * in[src]  (+bias, relu)
// Stage (col, dinv[col]) in LDS first: col read is coalesced, dinv gathers
// issue in PARALLEL across lanes. Gather loop then has a single-level
// dependence (LDS idx -> feature gather); unroll-4 gives 4 chains/group,
// 16 outstanding feature gathers per block.
template <int C, bool BIAS, bool RELU>
__global__ __launch_bounds__(C) void k_agg(const float* __restrict__ in, float* __restrict__ out,
                      const int* __restrict__ row_off, const int* __restrict__ col,
                      const float* __restrict__ dinv, const float* __restrict__ bias) {
    constexpr int LPG = C / 4;  // lanes per group (float4 each)
    constexpr int NG = 4;       // edge groups
    constexpr int MAXE = 256;   // staged edges per chunk
    __shared__ int sidx[MAXE];
    __shared__ float snrm[MAXE];
    __shared__ float4 red[NG][LPG];

    const int n = blockIdx.x;
    const int t = threadIdx.x;
    const int g = t / LPG;
    const int l = t % LPG;
    const int s = row_off[n], e = row_off[n + 1];
    const float4* __restrict__ in4 = (const float4*)in;

    float4 a0 = make_float4(0.f, 0.f, 0.f, 0.f);
    float4 a1 = make_float4(0.f, 0.f, 0.f, 0.f);
    float4 a2 = make_float4(0.f, 0.f, 0.f, 0.f);
    float4 a3 = make_float4(0.f, 0.f, 0.f, 0.f);

    for (int base = s; base < e; base += MAXE) {
        const int cnt = min(e - base, MAXE);
        for (int i = t; i < cnt; i += C) {
            int c = col[base + i];
            sidx[i] = c;
            snrm[i] = dinv[c];
        }
        __syncthreads();

        int k = g;
        for (; k + 3 * NG < cnt; k += 4 * NG) {
            int s0 = sidx[k];
            int s1 = sidx[k + NG];
            int s2 = sidx[k + 2 * NG];
            int s3 = sidx[k + 3 * NG];
            float d0 = snrm[k];
            float d1 = snrm[k + NG];
            float d2 = snrm[k + 2 * NG];
            float d3 = snrm[k + 3 * NG];
            float4 v0 = in4[(size_t)s0 * LPG + l];
            float4 v1 = in4[(size_t)s1 * LPG + l];
            float4 v2 = in4[(size_t)s2 * LPG + l];
            float4 v3 = in4[(size_t)s3 * LPG + l];
            a0.x = fmaf(d0, v0.x, a0.x); a0.y = fmaf(d0, v0.y, a0.y);
            a0.z = fmaf(d0, v0.z, a0.z); a0.w = fmaf(d0, v0.w, a0.w);
            a1.x = fmaf(d1, v1.x, a1.x); a1.y = fmaf(d1, v1.y, a1.y);
            a1.z = fmaf(d1, v1.z, a1.z); a1.w = fmaf(d1, v1.w, a1.w);
            a2.x = fmaf(d2, v2.x, a2.x); a2.y = fmaf(d2, v2.y, a2.y);
            a2.z = fmaf(d2, v2.z, a2.z); a2.w = fmaf(d2, v2.w, a2.w);
            a3.x = fmaf(d3, v3.x, a3.x); a3.y = fmaf(d3, v3.y, a3.y);
            a3.z = fmaf(d3, v3.z, a3.z); a3.w = fmaf(d3, v3.w, a3.w);
        }
        for (; k < cnt; k += NG) {
            int s0 = sidx[k];
            float d0 = snrm[k];
            float4 v0 = in4[(size_t)s0 * LPG + l];
            a0.x = fmaf(d0, v0.x, a0.x); a0.y = fmaf(d0, v0.y, a0.y);
            a0.z = fmaf(d0, v0.z, a0.z); a0.w = fmaf(d0, v0.w, a0.w);
        }
        __syncthreads();  // protect sidx/snrm before next chunk
    }

    a0.x += a1.x + a2.x + a3.x;
    a0.y += a1.y + a2.y + a3.y;
    a0.z += a1.z + a2.z + a3.z;
    a0.w += a1.w + a2.w + a3.w;
    red[g][l] = a0;
    __syncthreads();
    if (g == 0) {
        float4 r = red[0][l];
        float4 r1 = red[1][l];
        float4 r2 = red[2][l];
        float4 r3 = red[3][l];
        r.x += r1.x + r2.x + r3.x;
        r.y += r1.y + r2.y + r3.y;
        r.z += r1.z + r2.z + r3.z;
        r.w += r1.w + r2.w + r3.w;
        float dn = dinv[n];
        r.x *= dn; r.y *= dn; r.z *= dn; r.w *= dn;
        if constexpr (BIAS) {
            float4 bv = ((const float4*)bias)[l];
            r.x += bv.x; r.y += bv.y; r.z += bv.z; r.w += bv.w;
        }
        if constexpr (RELU) {
            r.x = fmaxf(r.x, 0.f); r.y = fmaxf(r.y, 0.f);
            r.z = fmaxf(r.z, 0.f); r.w = fmaxf(r.w, 0.f);
        }
        ((float4*)out)[(size_t)n * LPG + l] = r;
    }
}

// ---------------- f32 register-tiled GEMM: out[nrows,COUT] = in[nrows,K] @ W[K,COUT] ----
template <int K, int COUT, bool BIAS>
__global__ __launch_bounds__(256) void k_gemm(const float* __restrict__ in,
                                              const float* __restrict__ W,
                                              const float* __restrict__ bias,
                                              float* __restrict__ out, int nrows) {
    constexpr int TC = COUT / 4;   // thread-cols
    constexpr int TR = 256 / TC;   // thread-rows
    constexpr int ROWS = TR * 4;   // rows per block
    constexpr int KC = 32;         // k-chunk
    constexpr int KQ = KC / 4;

    __shared__ float Ws[KC][COUT];
    __shared__ float xsT[KC][ROWS];

    const int t = threadIdx.x;
    const int tc = t % TC;
    const int tr = t / TC;
    const int row0 = blockIdx.x * ROWS;

    float acc[4][4];
#pragma unroll
    for (int i = 0; i < 4; ++i)
#pragma unroll
        for (int j = 0; j < 4; ++j) acc[i][j] = 0.f;

    for (int kc = 0; kc < K; kc += KC) {
        __syncthreads();
        {
            constexpr int TOT = KC * COUT / 4;
            const float4* Wv = (const float4*)(W + (size_t)kc * COUT);
            float4* Wsv = (float4*)(&Ws[0][0]);
            for (int i = t; i < TOT; i += 256) Wsv[i] = Wv[i];
        }
        {
            for (int idx = t; idx < ROWS * KQ; idx += 256) {
                int r = idx / KQ, kq = idx % KQ;
                int row = row0 + r;
                if (row >= nrows) row = nrows - 1;
                float4 v = *(const float4*)(in + (size_t)row * K + kc + kq * 4);
                int kk = kq * 4;
                xsT[kk + 0][r] = v.x;
                xsT[kk + 1][r] = v.y;
                xsT[kk + 2][r] = v.z;
                xsT[kk + 3][r] = v.w;
            }
        }
        __syncthreads();
#pragma unroll
        for (int k = 0; k < KC; ++k) {
            float4 xv = *(const float4*)(&xsT[k][tr * 4]);
            float4 wv = *(const float4*)(&Ws[k][tc * 4]);
            acc[0][0] = fmaf(xv.x, wv.x, acc[0][0]);
            acc[0][1] = fmaf(xv.x, wv.y, acc[0][1]);
            acc[0][2] = fmaf(xv.x, wv.z, acc[0][2]);
            acc[0][3] = fmaf(xv.x, wv.w, acc[0][3]);
            acc[1][0] = fmaf(xv.y, wv.x, acc[1][0]);
            acc[1][1] = fmaf(xv.y, wv.y, acc[1][1]);
            acc[1][2] = fmaf(xv.y, wv.z, acc[1][2]);
            acc[1][3] = fmaf(xv.y, wv.w, acc[1][3]);
            acc[2][0] = fmaf(xv.z, wv.x, acc[2][0]);
            acc[2][1] = fmaf(xv.z, wv.y, acc[2][1]);
            acc[2][2] = fmaf(xv.z, wv.z, acc[2][2]);
            acc[2][3] = fmaf(xv.z, wv.w, acc[2][3]);
            acc[3][0] = fmaf(xv.w, wv.x, acc[3][0]);
            acc[3][1] = fmaf(xv.w, wv.y, acc[3][1]);
            acc[3][2] = fmaf(xv.w, wv.z, acc[3][2]);
            acc[3][3] = fmaf(xv.w, wv.w, acc[3][3]);
        }
    }

    float4 bv = make_float4(0.f, 0.f, 0.f, 0.f);
    if constexpr (BIAS) bv = *(const float4*)(bias + tc * 4);
#pragma unroll
    for (int i = 0; i < 4; ++i) {
        int row = row0 + tr * 4 + i;
        if (row < nrows) {
            float4 o;
            o.x = acc[i][0] + bv.x;
            o.y = acc[i][1] + bv.y;
            o.z = acc[i][2] + bv.z;
            o.w = acc[i][3] + bv.w;
            *(float4*)(out + (size_t)row * COUT + tc * 4) = o;
        }
    }
}

// ---------------- host ----------------
extern "C" void kernel_launch(void* const* d_in, const int* in_sizes, int n_in,
                              void* d_out, int out_size, void* d_ws, size_t ws_size,
                              hipStream_t stream) {
    const float* x = (const float*)d_in[0];
    const void* ei = d_in[1];
    const float* W1 = (const float*)d_in[2];
    const float* b1 = (const float*)d_in[3];
    const float* W2 = (const float*)d_in[4];
    const float* b2 = (const float*)d_in[5];
    const float* W3 = (const float*)d_in[6];
    const float* b3 = (const float*)d_in[7];
    float* out = (float*)d_out;

    char* ws = (char*)d_ws;
    size_t off = 0;
    auto alloc = [&](size_t bytes) -> void* {
        void* p = ws + off;
        off = (off + bytes + 255) & ~(size_t)255;
        return p;
    };

    int* flag = (int*)alloc(sizeof(int));
    int* deg = (int*)alloc((size_t)NND * 4);
    int* cursor = (int*)alloc((size_t)NND * 4);
    int* row_off = (int*)alloc((size_t)(NND + 1) * 4);
    int* bsum = (int*)alloc(512);
    float* dinv = (float*)alloc((size_t)NND * 4);
    int* col = (int*)alloc((size_t)NEP * 4);
    float* AX = (float*)alloc((size_t)NND * 128 * 4);  // aliased as H2 later
    float* A1 = (float*)alloc((size_t)NND * 256 * 4);  // aliased as H3 later
    float* A2 = (float*)alloc((size_t)NND * 128 * 4);
    float* H2 = AX;  // AX dead after gemm1
    float* H3 = A1;  // A1 dead after gemm2

    hipMemsetAsync(deg, 0, (size_t)NND * 4, stream);
    hipMemsetAsync(cursor, 0, (size_t)NND * 4, stream);

    k_detect<<<1, 256, 0, stream>>>((const long long*)ei, flag);

    const int gE = (NEP + 255) / 256;
    const int gN = (NND + 255) / 256;
    k_deg<<<gE, 256, 0, stream>>>(ei, flag, deg);
    k_dinv<<<gN, 256, 0, stream>>>(deg, dinv);

    const int NB = (NND + 1023) / 1024;  // 98
    k_scan1<<<NB, 1024, 0, stream>>>(deg, row_off, bsum);
    k_scan2<<<1, 128, 0, stream>>>(bsum, NB);
    k_scan3<<<gN, 256, 0, stream>>>(row_off, bsum);

    k_fill<<<gE, 256, 0, stream>>>(ei, flag, row_off, cursor, col);

    // L1: AX = Ahat @ X ; A1 = AX @ W1 + b1
    k_agg<128, false, false><<<NND, 128, 0, stream>>>(x, AX, row_off, col, dinv, nullptr);
    k_gemm<128, 256, true><<<(NND + 15) / 16, 256, 0, stream>>>(AX, W1, b1, A1, NND);

    // L2: H2 = A1 @ W2 ; A2 = relu(Ahat @ H2 + b2)
    k_gemm<256, 128, false><<<(NND + 31) / 32, 256, 0, stream>>>(A1, W2, nullptr, H2, NND);
    k_agg<128, true, true><<<NND, 128, 0, stream>>>(H2, A2, row_off, col, dinv, b2);

    // L3: H3 = A2 @ W3 ; out = Ahat @ H3 + b3
    k_gemm<128, 64, false><<<(NND + 63) / 64, 256, 0, stream>>>(A2, W3, nullptr, H3, NND);
    k_agg<64, true, false><<<NND, 64, 0, stream>>>(H3, out, row_off, col, dinv, b3);
}